// Round 5
// baseline (21674.989 us; speedup 1.0000x reference)
//
#include <hip/hip_runtime.h>
#include <cstdint>
#include <cstddef>

// ---------------------------------------------------------------------------
// RNNModel: 2-layer bidirectional GRU (B=64, T=1000, H=256) + FC(512->61) +
// length-gather.
// Round 5: gru_split_kernel — 16 WGs (2 dir x 4 sample-grp x 2 unit-halves).
//  - Each WG owns 128 hidden units: 24 B-frags/wave = 96 VGPRs => W_hh is
//    100% register-resident, ZERO W-LDS traffic (was 96 KB/step/CU).
//  - Halves exchange their h-half per step via global slots + device-scope
//    release/acquire flags (agent scope, correct under XCD non-coherence).
//    Partners bx^8 apart => same XCD under %8 round-robin (perf heuristic).
//  - Double-buffered h-LDS (2 x 16 x 288 u16) => ONE lgkm-only barrier/step.
//  - Bounded spin guard: a deadlock degrades to wrong output, not a hang.
// ---------------------------------------------------------------------------

typedef __attribute__((ext_vector_type(8))) __bf16 bf16x8;
typedef __attribute__((ext_vector_type(4))) float f32x4;
typedef __attribute__((ext_vector_type(4))) unsigned int u32x4;

#define AS1 __attribute__((address_space(1)))
#define AS3 __attribute__((address_space(3)))

#define SRZ  (-1.44269504089f)   // exp2 prescale for r,z rows
#define SN   (2.88539008177f)    // exp2 prescale for n rows

__device__ __forceinline__ void async_ld16(const void* g, void* l) {
  __builtin_amdgcn_global_load_lds((const AS1 unsigned int*)g,
                                   (AS3 unsigned int*)l, 16, 0, 0);
}

__device__ __forceinline__ f32x4 mfma16(u32x4 a, u32x4 b, f32x4 c) {
  return __builtin_amdgcn_mfma_f32_16x16x32_bf16(
      __builtin_bit_cast(bf16x8, a), __builtin_bit_cast(bf16x8, b), c, 0, 0, 0);
}

__device__ __forceinline__ unsigned short f2b(float f) {  // f32 -> bf16 RNE
  unsigned int u = __float_as_uint(f);
  u += 0x7fffu + ((u >> 16) & 1u);
  return (unsigned short)(u >> 16);
}
__device__ __forceinline__ float b2f(unsigned short s) {
  return __uint_as_float(((unsigned int)s) << 16);
}
__device__ __forceinline__ float gload(const float* p, size_t i) { return p[i]; }
__device__ __forceinline__ float gload(const unsigned short* p, size_t i) { return b2f(p[i]); }
__device__ __forceinline__ void gstore(float* p, size_t i, float v) { p[i] = v; }
__device__ __forceinline__ void gstore(unsigned short* p, size_t i, float v) { p[i] = f2b(v); }

__device__ __forceinline__ float sigm2(float xs) {  // sigma(x), xs = -log2e*x
  return __builtin_amdgcn_rcpf(1.0f + __builtin_amdgcn_exp2f(xs));
}
__device__ __forceinline__ float tanh2(float ys) {  // tanh(y), ys = 2log2e*y
  return __builtin_fmaf(-2.0f,
      __builtin_amdgcn_rcpf(1.0f + __builtin_amdgcn_exp2f(ys)), 1.0f);
}

// lgkm-only barrier: don't drain vmcnt (stores/prefetch stay in flight)
__device__ __forceinline__ void lds_barrier() {
  asm volatile("" ::: "memory");
  __builtin_amdgcn_s_waitcnt(0xC07F);  // vmcnt=63, expcnt=7, lgkmcnt=0
  __builtin_amdgcn_s_barrier();
  asm volatile("" ::: "memory");
}

// ---------------------------------------------------------------------------
__global__ void cast_bf16_kernel(const float* __restrict__ src,
                                 unsigned short* __restrict__ dst, int n) {
  const int i = blockIdx.x * 256 + threadIdx.x;
  if (i < n) dst[i] = f2b(src[i]);
}

// weight cast with per-gate-row exp2 prescale. rows: [0,512) r,z ; [512,768) n
__global__ void cast_w_kernel(const float* __restrict__ src,
                              unsigned short* __restrict__ dst, int n,
                              int in_dim) {
  const int i = blockIdx.x * 256 + threadIdx.x;
  if (i < n) {
    const int row = (i / in_dim) % 768;
    const float s = (row < 512) ? SRZ : SN;
    dst[i] = f2b(s * src[i]);
  }
}

// fused GEMM bias: scaled (b_ih + b_hh) for r,z rows; scaled b_ih for n rows
__global__ void bias_fuse_kernel(const float* __restrict__ bih,
                                 const float* __restrict__ bhh,
                                 float* __restrict__ fb) {
  const int n = blockIdx.x * 256 + threadIdx.x;  // 0..1535
  if (n < 1536) {
    const int dir = n / 768;
    const int rr = n - dir * 768;
    const float s = (rr < 512) ? SRZ : SN;
    float v = bih[dir * 768 + rr];
    if (rr < 512) v += bhh[dir * 768 + rr];
    fb[n] = s * v;
  }
}

__global__ void zero_flags_kernel(int* __restrict__ flags) {
  if (threadIdx.x < 32) flags[threadIdx.x] = 0;
}

// batch [B,T,8,40] -> x [T,B,320] bf16, x[t,b,f*8+c] = batch[b,t,c,f]
__global__ void transpose_x_kernel(const float* __restrict__ batch,
                                   unsigned short* __restrict__ xb) {
  const int t = blockIdx.x, b = blockIdx.y, i = threadIdx.x;  // block 320
  const float v = batch[((size_t)b * 1000 + t) * 320 + (i & 7) * 40 + (i >> 3)];
  xb[((size_t)t * 64 + b) * 320 + i] = f2b(v);
}

// ---------------------------------------------------------------------------
// C[M,N] = A[M,K](bf16) @ W[N,K](bf16)^T + bias[N]. CT = float or ushort(bf16).
// 128x128 tile, BK=32, 256 thr, m97 recipe (fragment-ordered LDS).
template <typename CT>
__global__ __launch_bounds__(256) void gemm_bt_kernel(
    const unsigned short* __restrict__ A, const unsigned short* __restrict__ W,
    const float* __restrict__ bias, CT* __restrict__ C, int M, int N, int K) {
  __shared__ __align__(16) unsigned short As[4096];
  __shared__ __align__(16) unsigned short Bs[4096];
  const int tid = threadIdx.x;
  const int lane = tid & 63;
  const int wv = tid >> 6;
  const int mBase = blockIdx.x * 128;
  const int nBase = blockIdx.y * 128;

  const int s0 = tid, s1 = tid + 256;
  const int r0 = ((s0 >> 6) << 4) | (s0 & 15), c0 = ((s0 >> 4) & 3) * 8;
  const int r1 = ((s1 >> 6) << 4) | (s1 & 15), c1 = ((s1 >> 4) & 3) * 8;

  const unsigned short* Arow0 = A + (size_t)(mBase + r0) * K + c0;
  const unsigned short* Arow1 = A + (size_t)(mBase + r1) * K + c1;
  const unsigned short* Wrow0 = W + (size_t)(nBase + r0) * K + c0;
  const unsigned short* Wrow1 = W + (size_t)(nBase + r1) * K + c1;

  char* lA = (char*)As;
  char* lB = (char*)Bs;
  char* dstA0 = lA + wv * 1024;
  char* dstA1 = lA + 4096 + wv * 1024;
  char* dstB0 = lB + wv * 1024;
  char* dstB1 = lB + 4096 + wv * 1024;

  f32x4 acc[4][4] = {};
  const int mh = (wv >> 1) * 64, nh = (wv & 1) * 64;
  const u32x4* As4 = (const u32x4*)As;
  const u32x4* Bs4 = (const u32x4*)Bs;

  for (int k0 = 0; k0 < K; k0 += 32) {
    __syncthreads();
    async_ld16(Arow0 + k0, dstA0);
    async_ld16(Arow1 + k0, dstA1);
    async_ld16(Wrow0 + k0, dstB0);
    async_ld16(Wrow1 + k0, dstB1);
    __syncthreads();
    u32x4 a[4], b[4];
#pragma unroll
    for (int mt = 0; mt < 4; ++mt) a[mt] = As4[((mh >> 4) + mt) * 64 + lane];
#pragma unroll
    for (int nt = 0; nt < 4; ++nt) b[nt] = Bs4[((nh >> 4) + nt) * 64 + lane];
#pragma unroll
    for (int mt = 0; mt < 4; ++mt)
#pragma unroll
      for (int nt = 0; nt < 4; ++nt)
        acc[mt][nt] = mfma16(a[mt], b[nt], acc[mt][nt]);
  }
#pragma unroll
  for (int nt = 0; nt < 4; ++nt) {
    const int n = nBase + nh + nt * 16 + (lane & 15);
    const float bn = bias[n];
#pragma unroll
    for (int mt = 0; mt < 4; ++mt) {
      const int mrow = mBase + mh + mt * 16 + ((lane >> 4) << 2);
#pragma unroll
      for (int r = 0; r < 4; ++r)
        gstore(C, (size_t)(mrow + r) * N + n, acc[mt][nt][r] + bn);
    }
  }
}

// ---------------------------------------------------------------------------
// Split GRU layer. grid=16: half=bx>>3, dir=bx&1, sgrp=(bx>>1)&3, partner=bx^8.
// 512 thr = 8 waves; wave w owns units [half*128+16w, +16): 3 gate tiles,
// 24 B-frags = 96 VGPRs (all W in regs). Thread (w,c,q): unit u'=16w+c,
// samples q*4+r. h-LDS double buffer [2][16][288] u16; one barrier/step.
// Cross-WG h-half exchange: slot[bx][par][128u'][16s] u16, release/acquire
// flags (agent scope). flag[bx] += 1 per wave per step (target 8*st).
template <typename GT>
__global__ __launch_bounds__(512, 2) void gru_split_kernel(
    const GT* __restrict__ gi,               // [T*B][1536] prescaled, bias folded
    const unsigned short* __restrict__ whh,  // [2][768][256] bf16 prescaled
    const float* __restrict__ bhh,           // [2][768] raw
    unsigned short* __restrict__ hout,       // [T*B][512] bf16
    unsigned short* __restrict__ slots,      // [16][2][128][16] u16
    int* __restrict__ flags) {               // [16]
  __shared__ __align__(16) char smem[18432];  // 2 x 16 x 576 B
  const int tid = threadIdx.x;
  const int lane = tid & 63;
  const int w = tid >> 6;   // 0..7
  const int c = lane & 15;
  const int q = lane >> 4;  // 0..3
  const int bx = blockIdx.x;
  const int half = bx >> 3;
  const int dir = bx & 1;
  const int sb = ((bx >> 1) & 3) * 16;
  const int pbx = bx ^ 8;

  for (int i = tid; i < 4608; i += 512) ((unsigned int*)smem)[i] = 0u;

  const int uh = 16 * w + c;       // unit within half [0,128)
  const int u = half * 128 + uh;   // unit within dir  [0,256)
  const float bhn = SN * bhh[dir * 768 + 512 + u];

  // B-frags (g,kt): row = g*256 + u, k = kt*32 + q*8
  const unsigned short* wb = whh + (size_t)dir * 196608 + (size_t)u * 256 + q * 8;
  u32x4 wv[3][8];
#pragma unroll
  for (int g = 0; g < 3; ++g)
#pragma unroll
    for (int kt = 0; kt < 8; ++kt)
      wv[g][kt] = *(const u32x4*)(wb + (size_t)g * 65536 + kt * 32);
#pragma unroll
  for (int g = 0; g < 3; ++g)
#pragma unroll
    for (int kt = 0; kt < 8; ++kt)
      asm volatile("" : "+v"(wv[g][kt]));  // pin: no in-loop remat

  float hv[4] = {0.f, 0.f, 0.f, 0.f};
  __syncthreads();

  const int t0 = dir ? 999 : 0;
  const GT* gp = gi + ((size_t)t0 * 64 + sb) * 1536 + dir * 768 + u;
  unsigned short* hp = hout + ((size_t)t0 * 64 + sb) * 512 + dir * 256 + u;
  const ptrdiff_t gstep = (dir ? -1 : 1) * (ptrdiff_t)(64 * 1536);
  const ptrdiff_t hstep = (dir ? -1 : 1) * (ptrdiff_t)(64 * 512);

  char* myslot = (char*)slots + (size_t)bx * 8192;
  char* pslot = (char*)slots + (size_t)pbx * 8192;
  int* myflag = flags + bx;
  int* pflag = flags + pbx;

  // consumer mapping: thread reads partner unit-row up, sample-quad qd
  const int up = tid >> 2, qd = tid & 3;
  const int ph = half ^ 1;

  for (int st = 0; st < 1000; ++st) {
    const int par = st & 1;         // slot/buf parity of h(st)
    const int ppar = par ^ 1;       // parity of h(st-1) = A-buf of this step
    char* abuf = smem + ppar * 9216;
    char* wbuf = smem + par * 9216;

    if (st > 0) {
      const int target = 8 * st;
      int guard = 0;
      while (__hip_atomic_load(pflag, __ATOMIC_RELAXED,
                               __HIP_MEMORY_SCOPE_AGENT) < target) {
        __builtin_amdgcn_s_sleep(1);
        if (++guard > (1 << 22)) break;  // no-hang fallback
      }
      __builtin_amdgcn_fence(__ATOMIC_ACQUIRE, "agent");
      const unsigned int* ps =
          (const unsigned int*)(pslot + ppar * 4096 + up * 32 + qd * 8);
      const unsigned int v0 = ps[0], v1 = ps[1];
      unsigned short* dst =
          (unsigned short*)(abuf + (qd * 4) * 576 + (ph * 128 + up) * 2);
      dst[0] = (unsigned short)(v0 & 0xffffu);
      dst[288] = (unsigned short)(v0 >> 16);
      dst[576] = (unsigned short)(v1 & 0xffffu);
      dst[864] = (unsigned short)(v1 >> 16);
    }
    lds_barrier();  // partner h visible; prev-step own writes ordered

    // A-frags: sample=c, k = q*8 + kt*32
    const char* hab = abuf + c * 576 + q * 16;
    u32x4 a[8];
#pragma unroll
    for (int kt = 0; kt < 8; ++kt) a[kt] = *(const u32x4*)(hab + kt * 64);

    // gi prefetch (consumed after MFMAs; latency hides under them)
    float p[3][4];
#pragma unroll
    for (int r = 0; r < 4; ++r)
#pragma unroll
      for (int g = 0; g < 3; ++g)
        p[g][r] = gload(gp, (size_t)(q * 4 + r) * 1536 + g * 256);

    f32x4 acc[3] = {};
#pragma unroll
    for (int kt = 0; kt < 8; ++kt)
#pragma unroll
      for (int g = 0; g < 3; ++g)
        acc[g] = mfma16(a[kt], wv[g][kt], acc[g]);

    // gates: thread owns unit u, samples s=q*4+r (C-row = q*4+reg)
    unsigned int packlo, packhi;
    {
      unsigned short hb[4];
#pragma unroll
      for (int r = 0; r < 4; ++r) {
        const float rr = sigm2(p[0][r] + acc[0][r]);
        const float zz = sigm2(p[1][r] + acc[1][r]);
        const float nn = tanh2(__builtin_fmaf(rr, acc[2][r] + bhn, p[2][r]));
        const float h = __builtin_fmaf(zz, hv[r] - nn, nn);
        hv[r] = h;
        hb[r] = f2b(h);
        ((unsigned short*)(wbuf + (q * 4 + r) * 576))[u] = hb[r];
        hp[(size_t)(q * 4 + r) * 512] = hb[r];
      }
      packlo = (unsigned int)hb[0] | ((unsigned int)hb[1] << 16);
      packhi = (unsigned int)hb[2] | ((unsigned int)hb[3] << 16);
    }
    unsigned int* ss = (unsigned int*)(myslot + par * 4096 + uh * 32 + q * 8);
    ss[0] = packlo;
    ss[1] = packhi;
    __builtin_amdgcn_fence(__ATOMIC_RELEASE, "agent");
    if (lane == 0)
      __hip_atomic_fetch_add(myflag, 1, __ATOMIC_RELAXED,
                             __HIP_MEMORY_SCOPE_AGENT);
    gp += gstep;
    hp += hstep;
  }
}

// ---------------------------------------------------------------------------
__global__ void prefix_kernel(const int* __restrict__ raw,
                              int* __restrict__ pref, int* __restrict__ lens) {
  if (threadIdx.x == 0) {
    const int stride = (raw[1] == 0 && raw[3] == 0 && raw[5] == 0) ? 2 : 1;
    int a = 0;
    for (int b = 0; b < 64; ++b) {
      const int L = raw[b * stride];
      pref[b] = a;
      lens[b] = L;
      a += L;
    }
  }
}

__global__ __launch_bounds__(256) void fc_kernel(
    const unsigned short* __restrict__ h2, const unsigned short* __restrict__ fcw,
    const float* __restrict__ fcb, const int* __restrict__ lens,
    const int* __restrict__ pref, float* __restrict__ out) {
  __shared__ __align__(16) unsigned short hrow[4][512];
  const int b = blockIdx.y;
  const int sub = threadIdx.x >> 6, lane = threadIdx.x & 63;
  const int t = blockIdx.x * 4 + sub;
  *(u32x4*)&hrow[sub][lane * 8] =
      *(const u32x4*)&h2[((size_t)t * 64 + b) * 512 + lane * 8];
  __syncthreads();
  const int len = lens[b];
  if (lane < 61 && t < len) {
    float acc = fcb[lane];
    const unsigned short* wr = fcw + (size_t)lane * 512;
#pragma unroll 4
    for (int k = 0; k < 512; k += 8) {
      u32x4 w4 = *(const u32x4*)(wr + k);
      u32x4 h4 = *(const u32x4*)(&hrow[sub][k]);
#pragma unroll
      for (int qq = 0; qq < 4; ++qq) {
        acc += __uint_as_float(w4[qq] << 16) * __uint_as_float(h4[qq] << 16);
        acc += __uint_as_float(w4[qq] & 0xffff0000u) * __uint_as_float(h4[qq] & 0xffff0000u);
      }
    }
    out[((size_t)pref[b] + t) * 61 + lane] = acc;
  }
}

// ---------------------------------------------------------------------------
template <typename GT>
static void run_pipeline(const float* batch, const int* lengths_raw,
                         const float* w_ih_l0, const float* w_hh_l0,
                         const float* b_ih_l0, const float* b_hh_l0,
                         const float* w_ih_l1, const float* w_hh_l1,
                         const float* b_ih_l1, const float* b_hh_l1,
                         const float* fc_w, const float* fc_b, float* out,
                         char* ws, hipStream_t stream) {
  size_t off = 0;
  auto alloc = [&](size_t bytes) -> char* {
    char* p = ws + off;
    off += (bytes + 255) & ~(size_t)255;
    return p;
  };
  char* pool = alloc((size_t)64000 * 512 * 2);  // xb/h1/h2 liveness-disjoint
  unsigned short* xb = (unsigned short*)pool;
  unsigned short* h1 = (unsigned short*)pool;
  unsigned short* h2 = (unsigned short*)pool;
  GT*             gi   = (GT*)alloc((size_t)64000 * 1536 * sizeof(GT));
  unsigned short* wih0 = (unsigned short*)alloc((size_t)1536 * 320 * 2);
  unsigned short* wih1 = (unsigned short*)alloc((size_t)1536 * 512 * 2);
  unsigned short* whh0 = (unsigned short*)alloc((size_t)1536 * 256 * 2);
  unsigned short* whh1 = (unsigned short*)alloc((size_t)1536 * 256 * 2);
  unsigned short* fcwb = (unsigned short*)alloc((size_t)61 * 512 * 2);
  float*          fb0  = (float*)alloc(1536 * 4);
  float*          fb1  = (float*)alloc(1536 * 4);
  unsigned short* slots = (unsigned short*)alloc(16 * 8192);
  int*            flg0 = (int*)alloc(64 * 4);
  int*            flg1 = flg0 + 16;
  int*            pref = (int*)alloc(256);
  int*            lens = (int*)alloc(256);

  auto castw = [&](const float* s, unsigned short* d, int n, int in_dim) {
    cast_w_kernel<<<dim3((n + 255) / 256), dim3(256), 0, stream>>>(s, d, n, in_dim);
  };
  castw(w_ih_l0, wih0, 2 * 768 * 320, 320);
  castw(w_hh_l0, whh0, 2 * 768 * 256, 256);
  castw(w_ih_l1, wih1, 2 * 768 * 512, 512);
  castw(w_hh_l1, whh1, 2 * 768 * 256, 256);
  cast_bf16_kernel<<<dim3((61 * 512 + 255) / 256), dim3(256), 0, stream>>>(
      fc_w, fcwb, 61 * 512);
  bias_fuse_kernel<<<dim3(6), dim3(256), 0, stream>>>(b_ih_l0, b_hh_l0, fb0);
  bias_fuse_kernel<<<dim3(6), dim3(256), 0, stream>>>(b_ih_l1, b_hh_l1, fb1);
  zero_flags_kernel<<<dim3(1), dim3(64), 0, stream>>>(flg0);

  transpose_x_kernel<<<dim3(1000, 64), dim3(320), 0, stream>>>(batch, xb);

  gemm_bt_kernel<GT><<<dim3(500, 12), dim3(256), 0, stream>>>(
      xb, wih0, fb0, gi, 64000, 1536, 320);
  gru_split_kernel<GT><<<dim3(16), dim3(512), 0, stream>>>(
      gi, whh0, b_hh_l0, h1, slots, flg0);
  gemm_bt_kernel<GT><<<dim3(500, 12), dim3(256), 0, stream>>>(
      h1, wih1, fb1, gi, 64000, 1536, 512);
  gru_split_kernel<GT><<<dim3(16), dim3(512), 0, stream>>>(
      gi, whh1, b_hh_l1, h2, slots, flg1);

  prefix_kernel<<<dim3(1), dim3(64), 0, stream>>>(lengths_raw, pref, lens);
  fc_kernel<<<dim3(250, 64), dim3(256), 0, stream>>>(h2, fcwb, fc_b, lens, pref, out);
}

extern "C" void kernel_launch(void* const* d_in, const int* in_sizes, int n_in,
                              void* d_out, int out_size, void* d_ws, size_t ws_size,
                              hipStream_t stream) {
  (void)in_sizes; (void)n_in; (void)out_size;
  const float* batch   = (const float*)d_in[0];
  const int*   lengths = (const int*)d_in[1];
  const float* w_ih_l0 = (const float*)d_in[2];
  const float* w_hh_l0 = (const float*)d_in[3];
  const float* b_ih_l0 = (const float*)d_in[4];
  const float* b_hh_l0 = (const float*)d_in[5];
  const float* w_ih_l1 = (const float*)d_in[6];
  const float* w_hh_l1 = (const float*)d_in[7];
  const float* b_ih_l1 = (const float*)d_in[8];
  const float* b_hh_l1 = (const float*)d_in[9];
  const float* fc_w    = (const float*)d_in[10];
  const float* fc_b    = (const float*)d_in[11];
  float* out = (float*)d_out;
  char* ws = (char*)d_ws;

  const size_t NEED_FP32 = 470000000ull;  // gi fp32 path peak
  if (ws_size >= NEED_FP32) {
    run_pipeline<float>(batch, lengths, w_ih_l0, w_hh_l0, b_ih_l0, b_hh_l0,
                        w_ih_l1, w_hh_l1, b_ih_l1, b_hh_l1, fc_w, fc_b, out,
                        ws, stream);
  } else {
    run_pipeline<unsigned short>(batch, lengths, w_ih_l0, w_hh_l0, b_ih_l0,
                                 b_hh_l0, w_ih_l1, w_hh_l1, b_ih_l1, b_hh_l1,
                                 fc_w, fc_b, out, ws, stream);
  }
}

// Round 6
// 5655.952 us; speedup vs baseline: 3.8322x; 3.8322x over previous
//
#include <hip/hip_runtime.h>
#include <cstdint>
#include <cstddef>

// ---------------------------------------------------------------------------
// RNNModel: 2-layer bidirectional GRU (B=64, T=1000, H=256) + FC(512->61) +
// length-gather.
// Round 6 (revert R5's cross-WG sync — 8.5us/step global handshake killed it):
//  - R4 topology: 8 WGs (2 dir x 4 sample-grp), 512 thr, recurrence in-WG.
//  - ALL 48 W_hh B-frags per wave in registers (192 regs -> AGPRs via pin);
//    ZERO W-LDS traffic (was 96 KB/step/CU, the R4 LDS-pipe wall).
//  - Double-buffered h-LDS (2x16x576 B static) => ONE lgkm-only barrier/step.
//  - gi stored TRANSPOSED [t][1536 gates][64 samples]: GEMM epilogue writes
//    f32x4 along samples; GRU gate phase does 6 vector loads (was 24 scalar).
//  - exp2-prescaled gates, moving pointers (unchanged from R4).
// ---------------------------------------------------------------------------

typedef __attribute__((ext_vector_type(8))) __bf16 bf16x8;
typedef __attribute__((ext_vector_type(4))) float f32x4;
typedef __attribute__((ext_vector_type(4))) unsigned int u32x4;
typedef __attribute__((ext_vector_type(2))) unsigned int u32x2;

#define AS1 __attribute__((address_space(1)))
#define AS3 __attribute__((address_space(3)))

#define SRZ  (-1.44269504089f)   // exp2 prescale for r,z rows
#define SN   (2.88539008177f)    // exp2 prescale for n rows

__device__ __forceinline__ void async_ld16(const void* g, void* l) {
  __builtin_amdgcn_global_load_lds((const AS1 unsigned int*)g,
                                   (AS3 unsigned int*)l, 16, 0, 0);
}

__device__ __forceinline__ f32x4 mfma16(u32x4 a, u32x4 b, f32x4 c) {
  return __builtin_amdgcn_mfma_f32_16x16x32_bf16(
      __builtin_bit_cast(bf16x8, a), __builtin_bit_cast(bf16x8, b), c, 0, 0, 0);
}

__device__ __forceinline__ unsigned short f2b(float f) {  // f32 -> bf16 RNE
  unsigned int u = __float_as_uint(f);
  u += 0x7fffu + ((u >> 16) & 1u);
  return (unsigned short)(u >> 16);
}
__device__ __forceinline__ float b2f(unsigned short s) {
  return __uint_as_float(((unsigned int)s) << 16);
}

// 4-wide load/store along the sample dim of the transposed gi
__device__ __forceinline__ f32x4 gload4(const float* p, size_t i) {
  return *(const f32x4*)(p + i);
}
__device__ __forceinline__ f32x4 gload4(const unsigned short* p, size_t i) {
  const u32x2 v = *(const u32x2*)(p + i);
  f32x4 r;
  r[0] = __uint_as_float(v[0] << 16);
  r[1] = __uint_as_float(v[0] & 0xffff0000u);
  r[2] = __uint_as_float(v[1] << 16);
  r[3] = __uint_as_float(v[1] & 0xffff0000u);
  return r;
}
__device__ __forceinline__ void gstore4(float* p, size_t i, f32x4 v) {
  *(f32x4*)(p + i) = v;
}
__device__ __forceinline__ void gstore4(unsigned short* p, size_t i, f32x4 v) {
  u32x2 o;
  o[0] = (unsigned int)f2b(v[0]) | ((unsigned int)f2b(v[1]) << 16);
  o[1] = (unsigned int)f2b(v[2]) | ((unsigned int)f2b(v[3]) << 16);
  *(u32x2*)(p + i) = o;
}

__device__ __forceinline__ float sigm2(float xs) {  // sigma(x), xs = -log2e*x
  return __builtin_amdgcn_rcpf(1.0f + __builtin_amdgcn_exp2f(xs));
}
__device__ __forceinline__ float tanh2(float ys) {  // tanh(y), ys = 2log2e*y
  return __builtin_fmaf(-2.0f,
      __builtin_amdgcn_rcpf(1.0f + __builtin_amdgcn_exp2f(ys)), 1.0f);
}

// lgkm-only barrier: don't drain vmcnt (stores/prefetch stay in flight)
__device__ __forceinline__ void lds_barrier() {
  asm volatile("" ::: "memory");
  __builtin_amdgcn_s_waitcnt(0xC07F);  // vmcnt=63, expcnt=7, lgkmcnt=0
  __builtin_amdgcn_s_barrier();
  asm volatile("" ::: "memory");
}

// ---------------------------------------------------------------------------
__global__ void cast_bf16_kernel(const float* __restrict__ src,
                                 unsigned short* __restrict__ dst, int n) {
  const int i = blockIdx.x * 256 + threadIdx.x;
  if (i < n) dst[i] = f2b(src[i]);
}

// weight cast with per-gate-row exp2 prescale. rows: [0,512) r,z ; [512,768) n
__global__ void cast_w_kernel(const float* __restrict__ src,
                              unsigned short* __restrict__ dst, int n,
                              int in_dim) {
  const int i = blockIdx.x * 256 + threadIdx.x;
  if (i < n) {
    const int row = (i / in_dim) % 768;
    const float s = (row < 512) ? SRZ : SN;
    dst[i] = f2b(s * src[i]);
  }
}

// fused GEMM bias: scaled (b_ih + b_hh) for r,z rows; scaled b_ih for n rows
__global__ void bias_fuse_kernel(const float* __restrict__ bih,
                                 const float* __restrict__ bhh,
                                 float* __restrict__ fb) {
  const int n = blockIdx.x * 256 + threadIdx.x;  // 0..1535
  if (n < 1536) {
    const int dir = n / 768;
    const int rr = n - dir * 768;
    const float s = (rr < 512) ? SRZ : SN;
    float v = bih[dir * 768 + rr];
    if (rr < 512) v += bhh[dir * 768 + rr];
    fb[n] = s * v;
  }
}

// batch [B,T,8,40] -> x [T,B,320] bf16, x[t,b,f*8+c] = batch[b,t,c,f]
__global__ void transpose_x_kernel(const float* __restrict__ batch,
                                   unsigned short* __restrict__ xb) {
  const int t = blockIdx.x, b = blockIdx.y, i = threadIdx.x;  // block 320
  const float v = batch[((size_t)b * 1000 + t) * 320 + (i & 7) * 40 + (i >> 3)];
  xb[((size_t)t * 64 + b) * 320 + i] = f2b(v);
}

// ---------------------------------------------------------------------------
// gi2[t][n][b] = A[t*64+b][:] . W[n][:] + bias[n].  A[M,K],W[N,K] bf16.
// 128x128 tile, BK=32, 256 thr, m97 recipe; epilogue stores f32x4 along b.
template <typename CT>
__global__ __launch_bounds__(256) void gemm_bt_kernel(
    const unsigned short* __restrict__ A, const unsigned short* __restrict__ W,
    const float* __restrict__ bias, CT* __restrict__ C, int M, int N, int K) {
  __shared__ __align__(16) unsigned short As[4096];
  __shared__ __align__(16) unsigned short Bs[4096];
  const int tid = threadIdx.x;
  const int lane = tid & 63;
  const int wv = tid >> 6;
  const int mBase = blockIdx.x * 128;
  const int nBase = blockIdx.y * 128;

  const int s0 = tid, s1 = tid + 256;
  const int r0 = ((s0 >> 6) << 4) | (s0 & 15), c0 = ((s0 >> 4) & 3) * 8;
  const int r1 = ((s1 >> 6) << 4) | (s1 & 15), c1 = ((s1 >> 4) & 3) * 8;

  const unsigned short* Arow0 = A + (size_t)(mBase + r0) * K + c0;
  const unsigned short* Arow1 = A + (size_t)(mBase + r1) * K + c1;
  const unsigned short* Wrow0 = W + (size_t)(nBase + r0) * K + c0;
  const unsigned short* Wrow1 = W + (size_t)(nBase + r1) * K + c1;

  char* lA = (char*)As;
  char* lB = (char*)Bs;
  char* dstA0 = lA + wv * 1024;
  char* dstA1 = lA + 4096 + wv * 1024;
  char* dstB0 = lB + wv * 1024;
  char* dstB1 = lB + 4096 + wv * 1024;

  f32x4 acc[4][4] = {};
  const int mh = (wv >> 1) * 64, nh = (wv & 1) * 64;
  const u32x4* As4 = (const u32x4*)As;
  const u32x4* Bs4 = (const u32x4*)Bs;

  for (int k0 = 0; k0 < K; k0 += 32) {
    __syncthreads();
    async_ld16(Arow0 + k0, dstA0);
    async_ld16(Arow1 + k0, dstA1);
    async_ld16(Wrow0 + k0, dstB0);
    async_ld16(Wrow1 + k0, dstB1);
    __syncthreads();
    u32x4 a[4], b[4];
#pragma unroll
    for (int mt = 0; mt < 4; ++mt) a[mt] = As4[((mh >> 4) + mt) * 64 + lane];
#pragma unroll
    for (int nt = 0; nt < 4; ++nt) b[nt] = Bs4[((nh >> 4) + nt) * 64 + lane];
#pragma unroll
    for (int mt = 0; mt < 4; ++mt)
#pragma unroll
      for (int nt = 0; nt < 4; ++nt)
        acc[mt][nt] = mfma16(a[mt], b[nt], acc[mt][nt]);
  }
  // epilogue: rows mrow..mrow+3 share t (=mrow>>6); store 4 samples at once
#pragma unroll
  for (int nt = 0; nt < 4; ++nt) {
    const int n = nBase + nh + nt * 16 + (lane & 15);
    const float bn = bias[n];
#pragma unroll
    for (int mt = 0; mt < 4; ++mt) {
      const int mrow = mBase + mh + mt * 16 + ((lane >> 4) << 2);
      f32x4 v = acc[mt][nt];
#pragma unroll
      for (int r = 0; r < 4; ++r) v[r] += bn;
      const size_t idx = ((size_t)(mrow >> 6) * 1536 + n) * 64 + (mrow & 63);
      gstore4(C, idx, v);
    }
  }
}

// ---------------------------------------------------------------------------
// GRU layer, W fully register-resident. grid=8: dir=bx&1, sb=(bx>>1)*16.
// 512 thr = 8 waves; wave w owns units [32w,32w+32): unit tiles j=0,1
// (u=32w+16j+c), gate tiles g*256+32w+16j => 48 B-frags = 192 regs (pinned,
// compiler parks them in AGPRs; MFMA reads AGPR directly on gfx950).
// h-LDS double buffer [2][16 samples][288 u16]; ONE lgkm barrier/step.
// Thread (w,c,q): units u0=32w+c, u1=u0+16; samples q*4+r (MFMA C-rows).
template <typename GT>
__global__ __launch_bounds__(512, 2) void gru_reg_kernel(
    const GT* __restrict__ gi2,              // [T][1536][64] prescaled+bias
    const unsigned short* __restrict__ whh,  // [2][768][256] bf16 prescaled
    const float* __restrict__ bhh,           // [2][768] raw
    unsigned short* __restrict__ hout) {     // [T*B][512] bf16
  __shared__ __align__(16) char smem[18432];  // 2 x 16 x 576
  const int tid = threadIdx.x;
  const int lane = tid & 63;
  const int w = tid >> 6;   // 0..7
  const int c = lane & 15;
  const int q = lane >> 4;  // 0..3
  const int dir = blockIdx.x & 1;
  const int sb = (blockIdx.x >> 1) * 16;

  for (int i = tid; i < 4608; i += 512) ((unsigned int*)smem)[i] = 0u;

  const int u0 = 32 * w + c;  // j=0 unit; j=1 is u0+16
  const float bhn0 = SN * bhh[dir * 768 + 512 + u0];
  const float bhn1 = SN * bhh[dir * 768 + 512 + u0 + 16];

  // B-frags (j,g,kt): row = g*256 + u0 + 16j, k = kt*32 + q*8
  const unsigned short* wb =
      whh + (size_t)dir * 196608 + (size_t)u0 * 256 + q * 8;
  u32x4 wv[2][3][8];
#pragma unroll
  for (int j = 0; j < 2; ++j)
#pragma unroll
    for (int g = 0; g < 3; ++g) {
      const unsigned short* p = wb + (size_t)(g * 256 + 16 * j) * 256;
#pragma unroll
      for (int kt = 0; kt < 8; ++kt) wv[j][g][kt] = *(const u32x4*)(p + kt * 32);
    }
#pragma unroll
  for (int j = 0; j < 2; ++j)
#pragma unroll
    for (int g = 0; g < 3; ++g)
#pragma unroll
      for (int kt = 0; kt < 8; ++kt)
        asm volatile("" : "+v"(wv[j][g][kt]));  // pin: no in-loop remat

  float h0[4] = {0.f, 0.f, 0.f, 0.f}, h1[4] = {0.f, 0.f, 0.f, 0.f};
  __syncthreads();

  const int t0 = dir ? 999 : 0;
  // gi2 element: (t*1536 + dir*768 + g*256 + u)*64 + b
  const GT* gp = gi2 + ((size_t)t0 * 1536 + dir * 768 + u0) * 64 + sb + q * 4;
  unsigned short* hp = hout + ((size_t)t0 * 64 + sb) * 512 + dir * 256 + u0;
  const ptrdiff_t gstep = (dir ? -1 : 1) * (ptrdiff_t)(1536 * 64);
  const ptrdiff_t hstep = (dir ? -1 : 1) * (ptrdiff_t)(64 * 512);

  const int hw0 = q * 4 * 288 + u0;  // h-LDS write base (u16 units)

  for (int st = 0; st < 1000; ++st) {
    const int par = st & 1;
    const char* abuf = smem + (par ^ 1) * 9216;  // h(st-1)
    char* wbuf = (char*)smem + par * 9216;       // h(st)

    lds_barrier();  // prev writes visible; prev reads retired

    // A-frags: sample=c, k = q*8 + kt*32
    const char* hab = abuf + c * 576 + q * 16;
    u32x4 a[8];
#pragma unroll
    for (int kt = 0; kt < 8; ++kt) a[kt] = *(const u32x4*)(hab + kt * 64);

    // gi vector prefetch: 4 samples per load, 6 loads (latency under MFMAs)
    f32x4 p[2][3];
#pragma unroll
    for (int j = 0; j < 2; ++j)
#pragma unroll
      for (int g = 0; g < 3; ++g)
        p[j][g] = gload4(gp, (size_t)(g * 256 + 16 * j) * 64);

    f32x4 acc[2][3] = {};
#pragma unroll
    for (int kt = 0; kt < 8; ++kt)
#pragma unroll
      for (int j = 0; j < 2; ++j)
#pragma unroll
        for (int g = 0; g < 3; ++g)
          acc[j][g] = mfma16(a[kt], wv[j][g][kt], acc[j][g]);

    unsigned short* hls = (unsigned short*)wbuf;
#pragma unroll
    for (int r = 0; r < 4; ++r) {  // sample s = q*4+r (C-row = q*4+reg)
      const float rr0 = sigm2(p[0][0][r] + acc[0][0][r]);
      const float zz0 = sigm2(p[0][1][r] + acc[0][1][r]);
      const float nn0 = tanh2(__builtin_fmaf(rr0, acc[0][2][r] + bhn0, p[0][2][r]));
      const float hv0 = __builtin_fmaf(zz0, h0[r] - nn0, nn0);
      h0[r] = hv0;
      const float rr1 = sigm2(p[1][0][r] + acc[1][0][r]);
      const float zz1 = sigm2(p[1][1][r] + acc[1][1][r]);
      const float nn1 = tanh2(__builtin_fmaf(rr1, acc[1][2][r] + bhn1, p[1][2][r]));
      const float hv1 = __builtin_fmaf(zz1, h1[r] - nn1, nn1);
      h1[r] = hv1;
      const unsigned short hb0 = f2b(hv0), hb1 = f2b(hv1);
      hls[hw0 + r * 288] = hb0;
      hls[hw0 + r * 288 + 16] = hb1;
      hp[(size_t)(q * 4 + r) * 512] = hb0;
      hp[(size_t)(q * 4 + r) * 512 + 16] = hb1;
    }
    gp += gstep;
    hp += hstep;
  }
}

// ---------------------------------------------------------------------------
__global__ void prefix_kernel(const int* __restrict__ raw,
                              int* __restrict__ pref, int* __restrict__ lens) {
  if (threadIdx.x == 0) {
    const int stride = (raw[1] == 0 && raw[3] == 0 && raw[5] == 0) ? 2 : 1;
    int a = 0;
    for (int b = 0; b < 64; ++b) {
      const int L = raw[b * stride];
      pref[b] = a;
      lens[b] = L;
      a += L;
    }
  }
}

__global__ __launch_bounds__(256) void fc_kernel(
    const unsigned short* __restrict__ h2, const unsigned short* __restrict__ fcw,
    const float* __restrict__ fcb, const int* __restrict__ lens,
    const int* __restrict__ pref, float* __restrict__ out) {
  __shared__ __align__(16) unsigned short hrow[4][512];
  const int b = blockIdx.y;
  const int sub = threadIdx.x >> 6, lane = threadIdx.x & 63;
  const int t = blockIdx.x * 4 + sub;
  *(u32x4*)&hrow[sub][lane * 8] =
      *(const u32x4*)&h2[((size_t)t * 64 + b) * 512 + lane * 8];
  __syncthreads();
  const int len = lens[b];
  if (lane < 61 && t < len) {
    float acc = fcb[lane];
    const unsigned short* wr = fcw + (size_t)lane * 512;
#pragma unroll 4
    for (int k = 0; k < 512; k += 8) {
      u32x4 w4 = *(const u32x4*)(wr + k);
      u32x4 h4 = *(const u32x4*)(&hrow[sub][k]);
#pragma unroll
      for (int qq = 0; qq < 4; ++qq) {
        acc += __uint_as_float(w4[qq] << 16) * __uint_as_float(h4[qq] << 16);
        acc += __uint_as_float(w4[qq] & 0xffff0000u) * __uint_as_float(h4[qq] & 0xffff0000u);
      }
    }
    out[((size_t)pref[b] + t) * 61 + lane] = acc;
  }
}

// ---------------------------------------------------------------------------
template <typename GT>
static void run_pipeline(const float* batch, const int* lengths_raw,
                         const float* w_ih_l0, const float* w_hh_l0,
                         const float* b_ih_l0, const float* b_hh_l0,
                         const float* w_ih_l1, const float* w_hh_l1,
                         const float* b_ih_l1, const float* b_hh_l1,
                         const float* fc_w, const float* fc_b, float* out,
                         char* ws, hipStream_t stream) {
  size_t off = 0;
  auto alloc = [&](size_t bytes) -> char* {
    char* p = ws + off;
    off += (bytes + 255) & ~(size_t)255;
    return p;
  };
  char* pool = alloc((size_t)64000 * 512 * 2);  // xb/h1/h2 liveness-disjoint
  unsigned short* xb = (unsigned short*)pool;
  unsigned short* h1 = (unsigned short*)pool;
  unsigned short* h2 = (unsigned short*)pool;
  GT*             gi   = (GT*)alloc((size_t)64000 * 1536 * sizeof(GT));
  unsigned short* wih0 = (unsigned short*)alloc((size_t)1536 * 320 * 2);
  unsigned short* wih1 = (unsigned short*)alloc((size_t)1536 * 512 * 2);
  unsigned short* whh0 = (unsigned short*)alloc((size_t)1536 * 256 * 2);
  unsigned short* whh1 = (unsigned short*)alloc((size_t)1536 * 256 * 2);
  unsigned short* fcwb = (unsigned short*)alloc((size_t)61 * 512 * 2);
  float*          fb0  = (float*)alloc(1536 * 4);
  float*          fb1  = (float*)alloc(1536 * 4);
  int*            pref = (int*)alloc(256);
  int*            lens = (int*)alloc(256);

  auto castw = [&](const float* s, unsigned short* d, int n, int in_dim) {
    cast_w_kernel<<<dim3((n + 255) / 256), dim3(256), 0, stream>>>(s, d, n, in_dim);
  };
  castw(w_ih_l0, wih0, 2 * 768 * 320, 320);
  castw(w_hh_l0, whh0, 2 * 768 * 256, 256);
  castw(w_ih_l1, wih1, 2 * 768 * 512, 512);
  castw(w_hh_l1, whh1, 2 * 768 * 256, 256);
  cast_bf16_kernel<<<dim3((61 * 512 + 255) / 256), dim3(256), 0, stream>>>(
      fc_w, fcwb, 61 * 512);
  bias_fuse_kernel<<<dim3(6), dim3(256), 0, stream>>>(b_ih_l0, b_hh_l0, fb0);
  bias_fuse_kernel<<<dim3(6), dim3(256), 0, stream>>>(b_ih_l1, b_hh_l1, fb1);

  transpose_x_kernel<<<dim3(1000, 64), dim3(320), 0, stream>>>(batch, xb);

  gemm_bt_kernel<GT><<<dim3(500, 12), dim3(256), 0, stream>>>(
      xb, wih0, fb0, gi, 64000, 1536, 320);
  gru_reg_kernel<GT><<<dim3(8), dim3(512), 0, stream>>>(gi, whh0, b_hh_l0, h1);
  gemm_bt_kernel<GT><<<dim3(500, 12), dim3(256), 0, stream>>>(
      h1, wih1, fb1, gi, 64000, 1536, 512);
  gru_reg_kernel<GT><<<dim3(8), dim3(512), 0, stream>>>(gi, whh1, b_hh_l1, h2);

  prefix_kernel<<<dim3(1), dim3(64), 0, stream>>>(lengths_raw, pref, lens);
  fc_kernel<<<dim3(250, 64), dim3(256), 0, stream>>>(h2, fcwb, fc_b, lens, pref, out);
}

extern "C" void kernel_launch(void* const* d_in, const int* in_sizes, int n_in,
                              void* d_out, int out_size, void* d_ws, size_t ws_size,
                              hipStream_t stream) {
  (void)in_sizes; (void)n_in; (void)out_size;
  const float* batch   = (const float*)d_in[0];
  const int*   lengths = (const int*)d_in[1];
  const float* w_ih_l0 = (const float*)d_in[2];
  const float* w_hh_l0 = (const float*)d_in[3];
  const float* b_ih_l0 = (const float*)d_in[4];
  const float* b_hh_l0 = (const float*)d_in[5];
  const float* w_ih_l1 = (const float*)d_in[6];
  const float* w_hh_l1 = (const float*)d_in[7];
  const float* b_ih_l1 = (const float*)d_in[8];
  const float* b_hh_l1 = (const float*)d_in[9];
  const float* fc_w    = (const float*)d_in[10];
  const float* fc_b    = (const float*)d_in[11];
  float* out = (float*)d_out;
  char* ws = (char*)d_ws;

  const size_t NEED_FP32 = 470000000ull;  // gi fp32 path peak
  if (ws_size >= NEED_FP32) {
    run_pipeline<float>(batch, lengths, w_ih_l0, w_hh_l0, b_ih_l0, b_hh_l0,
                        w_ih_l1, w_hh_l1, b_ih_l1, b_hh_l1, fc_w, fc_b, out,
                        ws, stream);
  } else {
    run_pipeline<unsigned short>(batch, lengths, w_ih_l0, w_hh_l0, b_ih_l0,
                                 b_hh_l0, w_ih_l1, w_hh_l1, b_ih_l1, b_hh_l1,
                                 fc_w, fc_b, out, ws, stream);
  }
}